// Round 13
// baseline (192.391 us; speedup 1.0000x reference)
//
#include <hip/hip_runtime.h>

namespace {
constexpr int NB  = 131072;
constexpr int NJ  = 24;
constexpr int PAR[NJ] = {0,0,0,0,1,2,3,4,5,6,7,8,9,9,9,12,13,14,16,17,18,19,20,21};
constexpr int BLK = 256;   // 4 waves/block; 64 batches/block (4 lanes per batch)
}

typedef float f32x4 __attribute__((ext_vector_type(4)));

// Row-parallel FK: 4 lanes per batch, lane r owns row r of every global
// transform. Row recurrence is independent per row: rowr(Rg[j]) = rowr(Rg[pj])*L,
// tg[j][r] = rowr(Rg[pj])*rel + tg[pj][r]; row 3 == [0,0,0,1] follows the same
// code with myrow=0, tg=1. r appears only as VALUES (4 cndmask selects at j==0),
// never as an index -> no scratch, no divergence, no shuffles, no LDS, no
// barriers. 4-lane groups load identical addresses (merged in L1); oT stores:
// 4 lanes = contiguous 64B, j-loop covers 1536B/batch contiguously (nt stores,
// proven 38% win in round 12's A/B). Grid is 4x round 8 -> 2x+ waves/CU.
__global__ __launch_bounds__(BLK, 4) void pose_kernel(
    const float* __restrict__ rot,
    const float* __restrict__ pos,
    float* __restrict__ outT,
    float* __restrict__ outP)
{
    const int tid = blockIdx.x * BLK + threadIdx.x;
    const int r   = tid & 3;          // row index 0..3
    const int b   = tid >> 2;         // batch index

    const float* prow = pos + (size_t)b * 72;
    const float* rrow = rot + (size_t)b * 216;
    float* oT = outT + (size_t)b * 384;
    float* oP = outP + (size_t)b * 72;

    const bool r0 = (r == 0), r1 = (r == 1), r2 = (r == 2);

    float rows[NJ][3];   // my row of each global rotation (live-range pruned)
    float tg[NJ];        // my row of each global translation
    float carry1[9];     // pos of joints 5,6,7  (needed in group 1)
    float carry2[6];     // pos of joints 13,14  (needed in group 2)
    float Pg[24];        // current group's positions (batch-level, replicated)

    #pragma unroll
    for (int g = 0; g < 3; ++g) {
        // ---- group positions: 6 f4 loads, same addrs across the 4-lane group ----
        #pragma unroll
        for (int i = 0; i < 6; ++i) {
            f32x4 v = *reinterpret_cast<const f32x4*>(prow + 24 * g + 4 * i);
            Pg[4*i+0] = v.x; Pg[4*i+1] = v.y; Pg[4*i+2] = v.z; Pg[4*i+3] = v.w;
        }

        #pragma unroll
        for (int q = 0; q < 2; ++q) {          // quad of 4 joints
            // ---- rot for this quad: 9 f4 loads (identical across 4-lane group) ----
            float buf[36];
            #pragma unroll
            for (int i = 0; i < 9; ++i) {
                f32x4 v = *reinterpret_cast<const f32x4*>(rrow + 72 * g + 36 * q + 4 * i);
                buf[4*i+0] = v.x; buf[4*i+1] = v.y; buf[4*i+2] = v.z; buf[4*i+3] = v.w;
            }

            #pragma unroll
            for (int l = 0; l < 4; ++l) {
                const int j  = 8 * g + 4 * q + l;
                const int pj = PAR[j];
                const float* L = buf + 9 * l;   // static offset
                const int lj = 3 * j - 24 * g;  // this joint's pos within Pg

                if (j == 0) {
                    // my row of local rot (row 3 = zeros); my trans component
                    #pragma unroll
                    for (int k = 0; k < 3; ++k)
                        rows[0][k] = r0 ? L[k] : r1 ? L[3+k] : r2 ? L[6+k] : 0.0f;
                    tg[0] = r0 ? Pg[0] : r1 ? Pg[1] : r2 ? Pg[2] : 1.0f;
                } else {
                    float pxp, pyp, pzp;
                    if (pj >= 8 * g) {                  // parent in this group
                        const int lp = 3 * pj - 24 * g;
                        pxp = Pg[lp]; pyp = Pg[lp+1]; pzp = Pg[lp+2];
                    } else if (g == 1) {                // parent in {5,6,7}
                        const int ci = 3 * (pj - 5);
                        pxp = carry1[ci]; pyp = carry1[ci+1]; pzp = carry1[ci+2];
                    } else {                            // g==2, parent in {13,14}
                        const int ci = 3 * (pj - 13);
                        pxp = carry2[ci]; pyp = carry2[ci+1]; pzp = carry2[ci+2];
                    }
                    const float relx = Pg[lj]   - pxp;
                    const float rely = Pg[lj+1] - pyp;
                    const float relz = Pg[lj+2] - pzp;
                    #pragma unroll
                    for (int c = 0; c < 3; ++c) {
                        rows[j][c] = rows[pj][0] * L[c]
                                   + rows[pj][1] * L[3+c]
                                   + rows[pj][2] * L[6+c];
                    }
                    tg[j] = rows[pj][0] * relx + rows[pj][1] * rely
                          + rows[pj][2] * relz + tg[pj];
                }

                // ---- outputs: one f4 row (4 lanes -> contiguous 64B), nt ----
                const float px = Pg[lj], py = Pg[lj+1], pz = Pg[lj+2];
                const float ib = rows[j][0]*px + rows[j][1]*py + rows[j][2]*pz;
                f32x4 o = {rows[j][0], rows[j][1], rows[j][2], tg[j] - ib};
                __builtin_nontemporal_store(
                    o, reinterpret_cast<f32x4*>(oT + j * 16 + r * 4));
                if (r < 3) {
                    __builtin_nontemporal_store(tg[j], oP + 3 * j + r);
                }
            }
        }

        // ---- save cross-group parent positions (static) ----
        if (g == 0) {
            #pragma unroll
            for (int k = 0; k < 9; ++k) carry1[k] = Pg[15 + k];   // joints 5,6,7
        } else if (g == 1) {
            #pragma unroll
            for (int k = 0; k < 6; ++k) carry2[k] = Pg[15 + k];   // joints 13,14
        }
    }
}

extern "C" void kernel_launch(void* const* d_in, const int* in_sizes, int n_in,
                              void* d_out, int out_size, void* d_ws, size_t ws_size,
                              hipStream_t stream) {
    const float* rot = (const float*)d_in[0];
    const float* pos = (const float*)d_in[1];
    float* outT = (float*)d_out;
    float* outP = outT + (size_t)NB * NJ * 16;
    dim3 grid((NB * 4) / BLK), block(BLK);
    hipLaunchKernelGGL(pose_kernel, grid, block, 0, stream, rot, pos, outT, outP);
}

// Round 14
// 77.774 us; speedup vs baseline: 2.4737x; 2.4737x over previous
//
#include <hip/hip_runtime.h>

namespace {
constexpr int NB  = 131072;
constexpr int NJ  = 24;
constexpr int PAR[NJ] = {0,0,0,0,1,2,3,4,5,6,7,8,9,9,9,12,13,14,16,17,18,19,20,21};
constexpr int BLK = 64;          // one wave per block
constexpr int BPB = 16;          // batches per block (4 lanes per batch)
constexpr int QS  = 17;          // f4 stride/batch, oT stage (16 data + 1 pad)
constexpr int PSF = 28;          // float stride/batch, oP stage (24 data + 4 pad)
constexpr int LDSF4 = BPB * QS;  // 272 f4 = 4352 B -> LDS never the residency cap
}

typedef float f32x4 __attribute__((ext_vector_type(4)));

// Row-parallel FK (round 13) + LDS-transposed nt output stores (round 8):
// 4 lanes per batch, lane r owns row r of every global transform; row
// recurrence is row-independent: rowr(Rg[j]) = rowr(Rg[pj])*L[j],
// tg[j][r] = rowr(Rg[pj])*rel + tg[pj][r]; row 3 = [0,0,0,1] runs the same
// code (myrow=0, tg=1). r enters only as VALUES (cndmask at j==0), never an
// index -> no scratch. 4-lane groups load identical addresses (merged; round
// 13 measured FETCH unchanged). Outputs go through tiny LDS transposes so
// every nt store instruction covers full-line contiguous runs (round 13's
// direct 64B nt stores amplified writes 1.57x; rounds 7/8 measured these LDS
// patterns at compulsory traffic). Still 1 wave/block, ZERO barriers (in-order
// per-wave DS makes stage->read->restage safe). Grid = 8192 blocks -> up to
// 32 waves/CU available; VGPR (~<=128) should allow ~16+/CU vs round 8's 8.
__global__ __launch_bounds__(BLK) void pose_kernel(
    const float* __restrict__ rot,
    const float* __restrict__ pos,
    float* __restrict__ outT,
    float* __restrict__ outP)
{
    __shared__ __align__(16) f32x4 lds[LDSF4];
    float* ldsf = reinterpret_cast<float*>(lds);

    const int t  = threadIdx.x;
    const int r  = t & 3;           // row 0..3
    const int bl = t >> 2;          // local batch 0..15
    const int b0 = blockIdx.x * BPB;
    const int b  = b0 + bl;

    const float* prow = pos + (size_t)b * 72;
    const float* rrow = rot + (size_t)b * 216;

    const bool r0 = (r == 0), r1 = (r == 1), r2 = (r == 2);

    float rows[NJ][3];   // my row of each global rotation (liveness-pruned)
    float tg[NJ];        // my row-component of each global translation
    float carry1[9];     // pos of joints 5,6,7  (needed in group 1)
    float carry2[6];     // pos of joints 13,14  (needed in group 2)
    float Pg[24];        // current group's positions (replicated per 4 lanes)

    #pragma unroll
    for (int g = 0; g < 3; ++g) {
        // ---- group positions: 6 f4 loads (same addr within 4-lane group) ----
        #pragma unroll
        for (int i = 0; i < 6; ++i) {
            f32x4 v = *reinterpret_cast<const f32x4*>(prow + 24 * g + 4 * i);
            Pg[4*i+0] = v.x; Pg[4*i+1] = v.y; Pg[4*i+2] = v.z; Pg[4*i+3] = v.w;
        }

        #pragma unroll
        for (int q = 0; q < 2; ++q) {          // quad of 4 joints
            // ---- rot for this quad: 9 f4 loads (merged across 4-lane group) ----
            float buf[36];
            #pragma unroll
            for (int i = 0; i < 9; ++i) {
                f32x4 v = *reinterpret_cast<const f32x4*>(rrow + 72 * g + 36 * q + 4 * i);
                buf[4*i+0] = v.x; buf[4*i+1] = v.y; buf[4*i+2] = v.z; buf[4*i+3] = v.w;
            }

            #pragma unroll
            for (int l = 0; l < 4; ++l) {
                const int j  = 8 * g + 4 * q + l;
                const int pj = PAR[j];
                const float* L = buf + 9 * l;   // static offset
                const int lj = 3 * j - 24 * g;  // this joint's pos within Pg

                if (j == 0) {
                    #pragma unroll
                    for (int k = 0; k < 3; ++k)
                        rows[0][k] = r0 ? L[k] : r1 ? L[3+k] : r2 ? L[6+k] : 0.0f;
                    tg[0] = r0 ? Pg[0] : r1 ? Pg[1] : r2 ? Pg[2] : 1.0f;
                } else {
                    float pxp, pyp, pzp;
                    if (pj >= 8 * g) {                  // parent in this group
                        const int lp = 3 * pj - 24 * g;
                        pxp = Pg[lp]; pyp = Pg[lp+1]; pzp = Pg[lp+2];
                    } else if (g == 1) {                // parent in {5,6,7}
                        const int ci = 3 * (pj - 5);
                        pxp = carry1[ci]; pyp = carry1[ci+1]; pzp = carry1[ci+2];
                    } else {                            // g==2, parent in {13,14}
                        const int ci = 3 * (pj - 13);
                        pxp = carry2[ci]; pyp = carry2[ci+1]; pzp = carry2[ci+2];
                    }
                    const float relx = Pg[lj]   - pxp;
                    const float rely = Pg[lj+1] - pyp;
                    const float relz = Pg[lj+2] - pzp;
                    #pragma unroll
                    for (int c = 0; c < 3; ++c) {
                        rows[j][c] = rows[pj][0] * L[c]
                                   + rows[pj][1] * L[3+c]
                                   + rows[pj][2] * L[6+c];
                    }
                    tg[j] = rows[pj][0] * relx + rows[pj][1] * rely
                          + rows[pj][2] * relz + tg[pj];
                }

                // ---- stage my oT row of this joint into LDS ----
                const float px = Pg[lj], py = Pg[lj+1], pz = Pg[lj+2];
                const float ib = rows[j][0]*px + rows[j][1]*py + rows[j][2]*pz;
                lds[bl * QS + l * 4 + r] =
                    f32x4{rows[j][0], rows[j][1], rows[j][2], tg[j] - ib};
            }

            // ---- oT quad: coalesced nt write (4 batches x 256B per instr) ----
            {
                float* gp = outT + (size_t)b0 * 384 + (8 * g + 4 * q) * 16;
                #pragma unroll
                for (int i = 0; i < 4; ++i) {
                    int f = t + BLK * i;          // 256 f4 = 16 batches x 16
                    int br = f >> 4, col = f & 15;
                    f32x4 v = lds[br * QS + col];
                    __builtin_nontemporal_store(
                        v, reinterpret_cast<f32x4*>(gp + (size_t)br * 384 + col * 4));
                }
            }
        }

        // ---- oP for this group: stage 8 joints' tg, coalesced nt write ----
        if (r < 3) {
            #pragma unroll
            for (int jl = 0; jl < 8; ++jl)
                ldsf[bl * PSF + jl * 3 + r] = tg[8 * g + jl];
        }
        {
            float* gp = outP + (size_t)b0 * 72 + g * 24;
            #pragma unroll
            for (int i = 0; i < 2; ++i) {
                int f = t + BLK * i;              // 96 f4 = 16 batches x 6
                if (f < BPB * 6) {
                    int br = f / 6, col = f % 6;
                    f32x4 v = *reinterpret_cast<const f32x4*>(&ldsf[br * PSF + col * 4]);
                    __builtin_nontemporal_store(
                        v, reinterpret_cast<f32x4*>(gp + (size_t)br * 72 + col * 4));
                }
            }
        }

        // ---- save cross-group parent positions (static) ----
        if (g == 0) {
            #pragma unroll
            for (int k = 0; k < 9; ++k) carry1[k] = Pg[15 + k];   // joints 5,6,7
        } else if (g == 1) {
            #pragma unroll
            for (int k = 0; k < 6; ++k) carry2[k] = Pg[15 + k];   // joints 13,14
        }
    }
}

extern "C" void kernel_launch(void* const* d_in, const int* in_sizes, int n_in,
                              void* d_out, int out_size, void* d_ws, size_t ws_size,
                              hipStream_t stream) {
    const float* rot = (const float*)d_in[0];
    const float* pos = (const float*)d_in[1];
    float* outT = (float*)d_out;
    float* outP = outT + (size_t)NB * NJ * 16;
    dim3 grid(NB / BPB), block(BLK);
    hipLaunchKernelGGL(pose_kernel, grid, block, 0, stream, rot, pos, outT, outP);
}